// Round 5
// baseline (17066.763 us; speedup 1.0000x reference)
//
#include <hip/hip_runtime.h>
#include <math.h>

// ---------------------------------------------------------------------------
// Fused 16-layer LSTM pipeline (H=512, T=4096) + MLP head.
//
//  - 256 blocks = 16 layers x 16 blocks/layer, 1024 thr (16 waves), 1 per CU.
//    Layer l's blocks are {l, l+16, ...}: all ≡ l (mod 8) -> same XCD under
//    round-robin dispatch (perf heuristic only; protocol is agent-scope safe
//    regardless of placement).
//  - Per thread: 1 h-index x 4 gates x 16-k slice, weights f16-packed in
//    64 VGPRs. __launch_bounds__(1024,4) -> 4 waves/EU -> 256-VGPR budget
//    so the weights actually stay resident (round-4: no 2nd arg -> cap 64,
//    partial scratch spill).
//  - Ring atoms are {tag32 | 2xf16 h}: producer packs h to f16 and pairs via
//    intra-wave shfl; 256 words per layer-step. Consumers stage the payload
//    u32 straight into LDS (no convert on the consumer critical path).
//  - ONE barrier per step: vx AND vh parity-double-buffered; h-spin (waves
//    0-3) and x_{t+1}-prefetch spin (waves 8-15) run concurrently pre-BAR.
//  - Backpressure: every-8-steps progress flags, checked inside the x-stage
//    (off the h-critical path). RING=64 slots >> max skew.
// ---------------------------------------------------------------------------

#define T_SEQ 4096
#define HDIM  512
#define NL    16
#define BPL   16
#define NTH   1024
#define RING  64
#define RMASK 63
#define RW    256     // ring words per layer-step (2 h per word)

typedef unsigned long long u64;
typedef _Float16 half2v __attribute__((ext_vector_type(2)));

struct Args {
  const float* x;
  const float* Wih[NL]; const float* Whh[NL];
  const float* bih[NL]; const float* bhh[NL];
  u64* ring;        // [NL][RING][RW] tagged f16x2 h
  unsigned* prog;   // [(NL+1)*BPL] progress flags
  float* sout;      // [T_SEQ][HDIM]
};

__device__ __forceinline__ u64 aloadU(const u64* p) {
  return __hip_atomic_load(p, __ATOMIC_RELAXED, __HIP_MEMORY_SCOPE_AGENT);
}
__device__ __forceinline__ void astoreU(u64* p, u64 v) {
  __hip_atomic_store(p, v, __ATOMIC_RELAXED, __HIP_MEMORY_SCOPE_AGENT);
}
__device__ __forceinline__ unsigned aloadu(const unsigned* p) {
  return __hip_atomic_load(p, __ATOMIC_RELAXED, __HIP_MEMORY_SCOPE_AGENT);
}
__device__ __forceinline__ float sigm(float x) { return 1.f / (1.f + __expf(-x)); }
__device__ __forceinline__ float tanhx(float x) {
  const float e = __expf(-2.f * fabsf(x));
  return copysignf((1.f - e) / (1.f + e), x);
}

#if __has_builtin(__builtin_amdgcn_fdot2)
#define DOT2(w, v, acc) __builtin_amdgcn_fdot2((w), (v), (acc), false)
#else
__device__ __forceinline__ float DOT2(half2v w, half2v v, float acc) {
  return acc + (float)w.x * (float)v.x + (float)w.y * (float)v.y;
}
#endif

#define BC(u) __builtin_bit_cast(half2v, (u))
#define DOTS8(acc, W) \
  acc = DOT2(W[0], p0, acc); acc = DOT2(W[1], p1, acc); \
  acc = DOT2(W[2], p2, acc); acc = DOT2(W[3], p3, acc); \
  acc = DOT2(W[4], p4, acc); acc = DOT2(W[5], p5, acc); \
  acc = DOT2(W[6], p6, acc); acc = DOT2(W[7], p7, acc)

__global__ void __launch_bounds__(NTH, 4) lstm16_kernel(Args a)
{
  const int tid   = threadIdx.x;
  const int layer = blockIdx.x & 15;
  const int b     = blockIdx.x >> 4;
  const int hi    = tid >> 5;          // 0..31: h-index within block
  const int cs    = tid & 31;          // 0..31: k-chunk (16x + 16h floats)
  const int kx    = cs * 16;
  const int hq    = b * 32 + hi;
  const int D     = layer ? HDIM : 128;

  // ---- weights: 4 gates f16-packed, 64 VGPRs ----
  half2v wx[4][8], wh[4][8];
  float  bs[4];
  const bool xok = (kx + 16 <= D);
  #pragma unroll
  for (int q = 0; q < 4; ++q) {
    const int row = q * HDIM + hq;
    bs[q] = a.bih[layer][row] + a.bhh[layer][row];
    const float2* px = (const float2*)(a.Wih[layer] + (size_t)row * D + kx);
    const float2* ph = (const float2*)(a.Whh[layer] + (size_t)row * HDIM + kx);
    #pragma unroll
    for (int p = 0; p < 8; ++p) {
      const float2 t0 = xok ? px[p] : make_float2(0.f, 0.f);
      const float2 t1 = ph[p];
      half2v w0; w0.x = (_Float16)t0.x; w0.y = (_Float16)t0.y; wx[q][p] = w0;
      half2v w1; w1.x = (_Float16)t1.x; w1.y = (_Float16)t1.y; wh[q][p] = w1;
    }
  }

  // LDS: parity-double-buffered f16x2 vectors, stride 10 per 8 words
  // (b64 reads: lane L and L+16 share banks -> 2-way alias = free).
  __shared__ __align__(8) unsigned vx16[2][320];
  __shared__ __align__(8) unsigned vh16[2][320];

  u64* ringOwn        = a.ring + (size_t)layer * RING * RW;
  const u64* ringPrev = a.ring + (size_t)(layer ? layer - 1 : 0) * RING * RW;
  const unsigned* progNext = a.prog + (layer + 1) * BPL;
  unsigned* myprog         = a.prog + layer * BPL + b;

  // ---- stage x for step tt into vx16[tt&1] (waves 8-15; w=tid-512) ----
  auto stage_x = [&](int tt) {
    if (tid < 512) return;
    const int w = tid - 512;
    if (w >= RW) return;                          // waves 12-15 idle
    const int dst = (w >> 3) * 10 + (w & 7);
    if (layer == 0) {
      if (w < 64) {
        const float2 xv = *(const float2*)(a.x + (size_t)tt * 128 + 2 * w);
        half2v pk; pk.x = (_Float16)xv.x; pk.y = (_Float16)xv.y;
        vx16[tt & 1][dst] = __builtin_bit_cast(unsigned, pk);
      }
      if ((layer < NL - 1) && (w < BPL) && ((tt & 7) == 0))
        while ((int)aloadu(progNext + w) < tt - 40) __builtin_amdgcn_s_sleep(2);
    } else {
      const u64* xw = ringPrev + (size_t)(tt & RMASK) * RW + w;
      bool okbp = !((layer < NL - 1) && (w < BPL) && ((tt & 7) == 0));
      u64 u = aloadU(xw);
      bool ok = ((unsigned)(u >> 32) == (unsigned)(tt + 1));
      while (!__all(ok & okbp)) {
        if (!ok) {
          u = aloadU(xw);
          ok = ((unsigned)(u >> 32) == (unsigned)(tt + 1));
          if (!ok) __builtin_amdgcn_s_sleep(1);
        }
        if (!okbp) okbp = ((int)aloadu(progNext + w) >= tt - 40);
      }
      vx16[tt & 1][dst] = (unsigned)u;
    }
  };

  // prologue: zero LDS (masked k-region must not be NaN), stage x_0
  for (int i = tid; i < 640; i += NTH) {
    ((unsigned*)vx16)[i] = 0;
    ((unsigned*)vh16)[i] = 0;
  }
  __syncthreads();
  stage_x(0);
  __syncthreads();

  float cst = 0.f;   // replicated across the 32-lane group

  for (int t = 0; t < T_SEQ; ++t) {
    // ---- issue h tagged-load early (waves 0-3; hides under x-dots) ----
    u64 hu = 0; const u64* hw = ringOwn;
    const bool hp = (t > 0) && (tid < RW);
    if (hp) {
      hw = ringOwn + (size_t)((t - 1) & RMASK) * RW + tid;
      hu = aloadU(hw);
    }

    // ---- x-dots from vx16[t&1] (staged last iteration) ----
    float a0 = 0.f, a1 = 0.f, a2 = 0.f, a3 = 0.f;
    {
      const unsigned* vb = vx16[t & 1] + cs * 10;
      const uint2 u0 = *(const uint2*)(vb + 0);
      const uint2 u1 = *(const uint2*)(vb + 2);
      const uint2 u2 = *(const uint2*)(vb + 4);
      const uint2 u3 = *(const uint2*)(vb + 6);
      const half2v p0 = BC(u0.x), p1 = BC(u0.y), p2 = BC(u1.x), p3 = BC(u1.y);
      const half2v p4 = BC(u2.x), p5 = BC(u2.y), p6 = BC(u3.x), p7 = BC(u3.y);
      DOTS8(a0, wx[0]); DOTS8(a1, wx[1]); DOTS8(a2, wx[2]); DOTS8(a3, wx[3]);
    }

    // ---- finish h poll, stage payload (waves 0-3) ----
    if (hp) {
      bool ok = ((unsigned)(hu >> 32) == (unsigned)t);
      while (!__all(ok)) {
        if (!ok) { hu = aloadU(hw); ok = ((unsigned)(hu >> 32) == (unsigned)t); }
      }
      vh16[t & 1][(tid >> 3) * 10 + (tid & 7)] = (unsigned)hu;
    }

    // ---- prefetch x_{t+1} concurrently with the h spin (waves 8-15) ----
    if (t + 1 < T_SEQ) stage_x(t + 1);

    __syncthreads();   // single barrier per step

    // ---- h-dots ----
    if (t > 0) {
      const unsigned* vb = vh16[t & 1] + cs * 10;
      const uint2 u0 = *(const uint2*)(vb + 0);
      const uint2 u1 = *(const uint2*)(vb + 2);
      const uint2 u2 = *(const uint2*)(vb + 4);
      const uint2 u3 = *(const uint2*)(vb + 6);
      const half2v p0 = BC(u0.x), p1 = BC(u0.y), p2 = BC(u1.x), p3 = BC(u1.y);
      const half2v p4 = BC(u2.x), p5 = BC(u2.y), p6 = BC(u3.x), p7 = BC(u3.y);
      DOTS8(a0, wh[0]); DOTS8(a1, wh[1]); DOTS8(a2, wh[2]); DOTS8(a3, wh[3]);
    }

    // ---- reduce across 32 k-lanes ----
    #pragma unroll
    for (int d = 1; d < 32; d <<= 1) {
      a0 += __shfl_xor(a0, d); a1 += __shfl_xor(a1, d);
      a2 += __shfl_xor(a2, d); a3 += __shfl_xor(a3, d);
    }

    // ---- gates (replicated in the 32-lane group), pack, post ----
    const float gi = sigm(a0 + bs[0]);
    const float gf = sigm(a1 + bs[1]);
    const float gg = tanhx(a2 + bs[2]);
    const float go = sigm(a3 + bs[3]);
    cst = gf * cst + gi * gg;
    const float h = go * tanhx(cst);

    const unsigned hu16 =
        (unsigned)__builtin_bit_cast(unsigned short, (_Float16)h);
    const unsigned other = __shfl_down(hu16, 32);   // odd h-index of the pair
    if ((tid & 63) == 0) {
      const unsigned pay = hu16 | (other << 16);
      astoreU(ringOwn + (size_t)(t & RMASK) * RW + (b * 16 + (tid >> 6)),
              ((u64)(unsigned)(t + 1) << 32) | (u64)pay);
    }
    if (layer == NL - 1 && (tid & 31) == 0)
      a.sout[(size_t)t * HDIM + hq] = h;
    if (tid == 0 && (t & 7) == 7)
      __hip_atomic_store(myprog, (unsigned)(t + 1), __ATOMIC_RELAXED,
                         __HIP_MEMORY_SCOPE_AGENT);
  }
}

// ---------------- MLP head: (T,512) -> 64 -> 32 -> 16 ----------------
__global__ void __launch_bounds__(64) mlp_head_kernel(
    const float* __restrict__ S,
    const float* __restrict__ w1, const float* __restrict__ b1,
    const float* __restrict__ w2, const float* __restrict__ b2,
    const float* __restrict__ w3, const float* __restrict__ b3,
    float* __restrict__ out)
{
  const int r   = blockIdx.x;
  const int tid = threadIdx.x;
  __shared__ __align__(16) float hbuf[HDIM];
  __shared__ float a1[64];
  __shared__ float a2[32];

  #pragma unroll
  for (int u = 0; u < HDIM / 64; ++u)
    hbuf[u * 64 + tid] = S[(size_t)r * HDIM + u * 64 + tid];
  __syncthreads();

  float acc = b1[tid];
  {
    const float4* w4 = (const float4*)(w1 + (size_t)tid * HDIM);
    const float4* h4 = (const float4*)hbuf;
    #pragma unroll 8
    for (int k = 0; k < HDIM / 4; ++k) {
      const float4 wv = w4[k], hv = h4[k];
      acc = fmaf(wv.x, hv.x, acc); acc = fmaf(wv.y, hv.y, acc);
      acc = fmaf(wv.z, hv.z, acc); acc = fmaf(wv.w, hv.w, acc);
    }
  }
  a1[tid] = acc * sigm(acc);
  __syncthreads();

  if (tid < 32) {
    float acc2 = b2[tid];
    #pragma unroll
    for (int k = 0; k < 64; ++k) acc2 = fmaf(a1[k], w2[tid * 64 + k], acc2);
    a2[tid] = acc2 * sigm(acc2);
  }
  __syncthreads();

  if (tid < 16) {
    float acc3 = b3[tid];
    #pragma unroll
    for (int k = 0; k < 32; ++k) acc3 = fmaf(a2[k], w3[tid * 32 + k], acc3);
    out[(size_t)r * 16 + tid] = acc3;
  }
}

// ---------------------------------------------------------------------------
extern "C" void kernel_launch(void* const* d_in, const int* in_sizes, int n_in,
                              void* d_out, int out_size, void* d_ws, size_t ws_size,
                              hipStream_t stream)
{
  (void)in_sizes; (void)n_in; (void)out_size; (void)ws_size;

  const float* x     = (const float*)d_in[0];
  const float* eWih0 = (const float*)d_in[1];
  const float* eWhh0 = (const float*)d_in[2];
  const float* ebih0 = (const float*)d_in[3];
  const float* ebhh0 = (const float*)d_in[4];
  const float* eWih  = (const float*)d_in[5];
  const float* eWhh  = (const float*)d_in[6];
  const float* ebih  = (const float*)d_in[7];
  const float* ebhh  = (const float*)d_in[8];
  const float* dWih  = (const float*)d_in[9];
  const float* dWhh  = (const float*)d_in[10];
  const float* dbih  = (const float*)d_in[11];
  const float* dbhh  = (const float*)d_in[12];
  const float* fc1w  = (const float*)d_in[13];
  const float* fc1b  = (const float*)d_in[14];
  const float* fc2w  = (const float*)d_in[15];
  const float* fc2b  = (const float*)d_in[16];
  const float* fc3w  = (const float*)d_in[17];
  const float* fc3b  = (const float*)d_in[18];
  float* out = (float*)d_out;

  // ws layout: ring 2 MB | prog 4 KB | sout 8 MB
  const size_t RINGBYTES = (size_t)NL * RING * RW * sizeof(u64);  // 2 MB
  Args p{};
  p.x    = x;
  p.ring = (u64*)d_ws;
  p.prog = (unsigned*)((char*)d_ws + RINGBYTES);
  p.sout = (float*)((char*)d_ws + RINGBYTES + 4096);

  p.Wih[0] = eWih0; p.Whh[0] = eWhh0; p.bih[0] = ebih0; p.bhh[0] = ebhh0;
  for (int l = 1; l < 8; ++l) {
    p.Wih[l] = eWih + (size_t)(l - 1) * 4 * HDIM * HDIM;
    p.Whh[l] = eWhh + (size_t)(l - 1) * 4 * HDIM * HDIM;
    p.bih[l] = ebih + (size_t)(l - 1) * 4 * HDIM;
    p.bhh[l] = ebhh + (size_t)(l - 1) * 4 * HDIM;
  }
  for (int l = 8; l < 16; ++l) {
    p.Wih[l] = dWih + (size_t)(l - 8) * 4 * HDIM * HDIM;
    p.Whh[l] = dWhh + (size_t)(l - 8) * 4 * HDIM * HDIM;
    p.bih[l] = dbih + (size_t)(l - 8) * 4 * HDIM;
    p.bhh[l] = dbhh + (size_t)(l - 8) * 4 * HDIM;
  }

  // clear ring tags + progress flags each launch -> replay-safe
  hipMemsetAsync(d_ws, 0, RINGBYTES + 4096, stream);

  void* args[] = { &p };
  hipError_t e = hipLaunchCooperativeKernel((const void*)lstm16_kernel,
                                            dim3(NL * BPL), dim3(NTH), args, 0,
                                            stream);
  if (e != hipSuccess)   // 256 blocks @ 1/CU on 256 CUs: co-resident anyway
    lstm16_kernel<<<dim3(NL * BPL), dim3(NTH), 0, stream>>>(p);

  mlp_head_kernel<<<dim3(T_SEQ), dim3(64), 0, stream>>>(
      p.sout, fc1w, fc1b, fc2w, fc2b, fc3w, fc3b, out);
}

// Round 7
// 14748.242 us; speedup vs baseline: 1.1572x; 1.1572x over previous
//
#include <hip/hip_runtime.h>
#include <math.h>

// ---------------------------------------------------------------------------
// Fused 16-layer LSTM pipeline (H=512, T=4096) + MLP head.
//
//  - 256 blocks = 16 layers x 16 blocks/layer, 1024 thr (16 waves), 1/CU.
//  - Weights f16-packed in 64 u32/thread (register/AGPR-resident; r4/r5 FETCH
//    evidence shows no memory spill). fp32 accumulate via v_dot2_f32_f16.
//  - Protocol = r4 ordering (posts PRE-BAR2; r5 proved moving them after the
//    barrier serializes a compute phase into the h-cycle) with tighter atoms:
//      * ring words are u32 {tag16<<16 | f16 h}: self-consistent, no 64-bit
//        atomicity requirement; h-exchange = 2KB = 32 HBM lines per step.
//      * h-ring: 2 parity slots. Deadlock-free: sibling B can be at most one
//        step ahead (B's poll(t) requires our step-t post), so the slot we
//        poll holds tag t or stale <= t-2; equality check is safe.
//      * h-poll: waves 0-1 only (2 u64 atomic loads per lane = 4 h each).
//      * x-ring: 64 slots, sc1, prog-flag backpressure (skew-tolerant).
//  - All cross-CU ops are __hip_atomic_* agent scope (sc1) — the proven path.
//    (r6's sc0 "L2-local" experiment deadlocked: NOT coherent cross-CU.)
// ---------------------------------------------------------------------------

#define T_SEQ 4096
#define HDIM  512
#define NL    16
#define BPL   16
#define NTH   1024
#define XRING 64
#define XMASK 63

typedef unsigned long long u64;
typedef _Float16 half2v __attribute__((ext_vector_type(2)));

struct Args {
  const float* x;
  const float* Wih[NL]; const float* Whh[NL];
  const float* bih[NL]; const float* bhh[NL];
  unsigned* hring;  // [NL][2][HDIM]     u32 {tag16|f16}
  unsigned* xring;  // [NL][XRING][HDIM] u32 {tag16|f16}
  unsigned* prog;   // [(NL+1)*BPL]
  float* sout;      // [T_SEQ][HDIM]
};

__device__ __forceinline__ u64 aloadU(const u64* p) {
  return __hip_atomic_load(p, __ATOMIC_RELAXED, __HIP_MEMORY_SCOPE_AGENT);
}
__device__ __forceinline__ void astoreU(u64* p, u64 v) {
  __hip_atomic_store(p, v, __ATOMIC_RELAXED, __HIP_MEMORY_SCOPE_AGENT);
}
__device__ __forceinline__ unsigned aloadu(const unsigned* p) {
  return __hip_atomic_load(p, __ATOMIC_RELAXED, __HIP_MEMORY_SCOPE_AGENT);
}
__device__ __forceinline__ void astoreu(unsigned* p, unsigned v) {
  __hip_atomic_store(p, v, __ATOMIC_RELAXED, __HIP_MEMORY_SCOPE_AGENT);
}
__device__ __forceinline__ float sigm(float x) { return 1.f / (1.f + __expf(-x)); }
__device__ __forceinline__ float tanhx(float x) {
  const float e = __expf(-2.f * fabsf(x));
  return copysignf((1.f - e) / (1.f + e), x);
}

#if __has_builtin(__builtin_amdgcn_fdot2)
#define DOT2(w, v, acc) __builtin_amdgcn_fdot2((w), (v), (acc), false)
#else
__device__ __forceinline__ float DOT2(half2v w, half2v v, float acc) {
  return acc + (float)w.x * (float)v.x + (float)w.y * (float)v.y;
}
#endif

#define BC(u) __builtin_bit_cast(half2v, (u))
#define DOTS8(acc, W) \
  acc = DOT2(W[0], p0, acc); acc = DOT2(W[1], p1, acc); \
  acc = DOT2(W[2], p2, acc); acc = DOT2(W[3], p3, acc); \
  acc = DOT2(W[4], p4, acc); acc = DOT2(W[5], p5, acc); \
  acc = DOT2(W[6], p6, acc); acc = DOT2(W[7], p7, acc)

// LDS word index for f16-pair word w (stride 10 per 8 words: <=2-way alias)
#define DST(w) ((((w) >> 3) * 10) + ((w) & 7))

__global__ void __launch_bounds__(NTH) lstm16_kernel(Args a)
{
  const int tid   = threadIdx.x;
  const int layer = blockIdx.x & 15;
  const int b     = blockIdx.x >> 4;
  const int hi    = tid >> 5;          // 0..31: h-index within block
  const int cs    = tid & 31;          // 0..31: k-chunk (16x + 16h floats)
  const int kx    = cs * 16;
  const int hq    = b * 32 + hi;
  const int D     = layer ? HDIM : 128;

  // ---- weights: 4 gates x 2 sides, f16-packed, 64 u32 ----
  half2v wx[4][8], wh[4][8];
  float  bs[4];
  const bool xok = (kx + 16 <= D);
  #pragma unroll
  for (int q = 0; q < 4; ++q) {
    const int row = q * HDIM + hq;
    bs[q] = a.bih[layer][row] + a.bhh[layer][row];
    const float2* px = (const float2*)(a.Wih[layer] + (size_t)row * D + kx);
    const float2* ph = (const float2*)(a.Whh[layer] + (size_t)row * HDIM + kx);
    #pragma unroll
    for (int p = 0; p < 8; ++p) {
      const float2 t0 = xok ? px[p] : make_float2(0.f, 0.f);
      const float2 t1 = ph[p];
      half2v w0; w0.x = (_Float16)t0.x; w0.y = (_Float16)t0.y; wx[q][p] = w0;
      half2v w1; w1.x = (_Float16)t1.x; w1.y = (_Float16)t1.y; wh[q][p] = w1;
    }
  }

  __shared__ __align__(8) unsigned vx16[2][320];
  __shared__ __align__(8) unsigned vh16[2][320];
  for (int i = tid; i < 640; i += NTH) {
    ((unsigned*)vx16)[i] = 0;
    ((unsigned*)vh16)[i] = 0;
  }

  unsigned* hOwn        = a.hring + (size_t)layer * 2 * HDIM;
  unsigned* xOwn        = a.xring + (size_t)layer * XRING * HDIM;
  const unsigned* xPrev = a.xring + (size_t)(layer ? layer - 1 : 0) * XRING * HDIM;
  const unsigned* progNext = a.prog + (layer + 1) * BPL;
  unsigned* myprog         = a.prog + layer * BPL + b;

  // ---- stage x for step tt into vx16[tt&1] (waves 8-11; w = tid-512) ----
  auto stage_x = [&](int tt) {
    if (tid < 512 || tid >= 768) return;
    const int w = tid - 512;                       // 0..255: f16-pair word
    const unsigned tt16 = (unsigned)(tt + 1) & 0xffffu;
    bool okbp = !((layer < NL - 1) && (w < BPL) && ((tt & 7) == 0));
    if (layer == 0) {
      if (w < 64) {
        const float2 xv = *(const float2*)(a.x + (size_t)tt * 128 + 2 * w);
        half2v pk; pk.x = (_Float16)xv.x; pk.y = (_Float16)xv.y;
        vx16[tt & 1][DST(w)] = __builtin_bit_cast(unsigned, pk);
      }
      if (!okbp)
        while ((int)aloadu(progNext + w) < tt - 40) __builtin_amdgcn_s_sleep(2);
    } else {
      const u64* xw = (const u64*)(xPrev + (size_t)(tt & XMASK) * HDIM) + w;
      u64 u = aloadU(xw);
      bool ok = (((u >> 16) & 0xffffu) == tt16) && ((u >> 48) == tt16);
      while (!__all(ok & okbp)) {
        if (!ok) {
          u = aloadU(xw);
          ok = (((u >> 16) & 0xffffu) == tt16) && ((u >> 48) == tt16);
          if (!ok) __builtin_amdgcn_s_sleep(1);
        }
        if (!okbp) okbp = ((int)aloadu(progNext + w) >= tt - 40);
      }
      vx16[tt & 1][DST(w)] =
          (unsigned)(u & 0xffffu) | (((unsigned)(u >> 32) & 0xffffu) << 16);
    }
  };

  __syncthreads();      // LDS zero visible
  stage_x(0);
  __syncthreads();

  float cst = 0.f;      // replicated across each 32-lane k-group

  for (int t = 0; t < T_SEQ; ++t) {
    const int par = t & 1;
    const unsigned t16 = (unsigned)t & 0xffffu;

    // ---- issue h(t-1) poll early (waves 0-1; x-dots hide the RT) ----
    u64 hu0 = 0, hu1 = 0; const u64* hw = (const u64*)hOwn;
    const bool hp = (t > 0) && (tid < 128);
    if (hp) {
      hw  = (const u64*)(hOwn + (size_t)((t - 1) & 1) * HDIM) + 2 * tid;
      hu0 = aloadU(hw);
      hu1 = aloadU(hw + 1);
    }

    // ---- x-dots from vx16[par] (staged last iteration) ----
    float a0 = 0.f, a1 = 0.f, a2 = 0.f, a3 = 0.f;
    {
      const unsigned* vb = vx16[par] + cs * 10;
      const uint2 u0 = *(const uint2*)(vb + 0);
      const uint2 u1 = *(const uint2*)(vb + 2);
      const uint2 u2 = *(const uint2*)(vb + 4);
      const uint2 u3 = *(const uint2*)(vb + 6);
      const half2v p0 = BC(u0.x), p1 = BC(u0.y), p2 = BC(u1.x), p3 = BC(u1.y);
      const half2v p4 = BC(u2.x), p5 = BC(u2.y), p6 = BC(u3.x), p7 = BC(u3.y);
      DOTS8(a0, wx[0]); DOTS8(a1, wx[1]); DOTS8(a2, wx[2]); DOTS8(a3, wx[3]);
    }

    // ---- finish h poll (4 tags per lane), stage payload ----
    if (hp) {
      bool ok = (((hu0 >> 16) & 0xffffu) == t16) && ((hu0 >> 48) == t16) &&
                (((hu1 >> 16) & 0xffffu) == t16) && ((hu1 >> 48) == t16);
      while (!__all(ok)) {
        if (!ok) {
          hu0 = aloadU(hw);
          hu1 = aloadU(hw + 1);
          ok = (((hu0 >> 16) & 0xffffu) == t16) && ((hu0 >> 48) == t16) &&
               (((hu1 >> 16) & 0xffffu) == t16) && ((hu1 >> 48) == t16);
        }
      }
      vh16[par][DST(2 * tid)] =
          (unsigned)(hu0 & 0xffffu) | (((unsigned)(hu0 >> 32) & 0xffffu) << 16);
      vh16[par][DST(2 * tid + 1)] =
          (unsigned)(hu1 & 0xffffu) | (((unsigned)(hu1 >> 32) & 0xffffu) << 16);
    }

    // ---- stage x(t+1) concurrently with the h spin (waves 8-11) ----
    if (t + 1 < T_SEQ) stage_x(t + 1);

    __syncthreads();   // BAR1: vh/vx staged

    // ---- h-dots ----
    if (t > 0) {
      const unsigned* vb = vh16[par] + cs * 10;
      const uint2 u0 = *(const uint2*)(vb + 0);
      const uint2 u1 = *(const uint2*)(vb + 2);
      const uint2 u2 = *(const uint2*)(vb + 4);
      const uint2 u3 = *(const uint2*)(vb + 6);
      const half2v p0 = BC(u0.x), p1 = BC(u0.y), p2 = BC(u1.x), p3 = BC(u1.y);
      const half2v p4 = BC(u2.x), p5 = BC(u2.y), p6 = BC(u3.x), p7 = BC(u3.y);
      DOTS8(a0, wh[0]); DOTS8(a1, wh[1]); DOTS8(a2, wh[2]); DOTS8(a3, wh[3]);
    }

    // ---- reduce across 32 k-lanes ----
    #pragma unroll
    for (int d = 1; d < 32; d <<= 1) {
      a0 += __shfl_xor(a0, d); a1 += __shfl_xor(a1, d);
      a2 += __shfl_xor(a2, d); a3 += __shfl_xor(a3, d);
    }

    // ---- gates, pack, POST (pre-BAR2: drained before siblings repoll) ----
    const float gi = sigm(a0 + bs[0]);
    const float gf = sigm(a1 + bs[1]);
    const float gg = tanhx(a2 + bs[2]);
    const float go = sigm(a3 + bs[3]);
    cst = gf * cst + gi * gg;
    const float h = go * tanhx(cst);

    const unsigned tagw =
        ((unsigned)(t + 1) & 0xffffu) << 16;
    const unsigned w0 = tagw |
        (unsigned)__builtin_bit_cast(unsigned short, (_Float16)h);
    const unsigned w1 = __shfl_down(w0, 32);        // partner h (odd index)
    if ((tid & 63) == 0) {
      const u64 word = ((u64)w1 << 32) | (u64)w0;
      const int widx = b * 16 + (tid >> 6);         // u64 index 0..255
      astoreU((u64*)(hOwn + (size_t)(t & 1) * HDIM) + widx, word);
      if (layer < NL - 1)
        astoreU((u64*)(xOwn + (size_t)(t & XMASK) * HDIM) + widx, word);
    }
    if (layer == NL - 1 && cs == 0)
      a.sout[(size_t)t * HDIM + hq] = h;
    if (tid == 0 && (t & 7) == 7)
      astoreu(myprog, (unsigned)(t + 1));

    __syncthreads();   // BAR2: posts drained (vmcnt 0) before next poll round
  }
}

// ---------------- MLP head: (T,512) -> 64 -> 32 -> 16 ----------------
__global__ void __launch_bounds__(64) mlp_head_kernel(
    const float* __restrict__ S,
    const float* __restrict__ w1, const float* __restrict__ b1,
    const float* __restrict__ w2, const float* __restrict__ b2,
    const float* __restrict__ w3, const float* __restrict__ b3,
    float* __restrict__ out)
{
  const int r   = blockIdx.x;
  const int tid = threadIdx.x;
  __shared__ __align__(16) float hbuf[HDIM];
  __shared__ float a1[64];
  __shared__ float a2[32];

  #pragma unroll
  for (int u = 0; u < HDIM / 64; ++u)
    hbuf[u * 64 + tid] = S[(size_t)r * HDIM + u * 64 + tid];
  __syncthreads();

  float acc = b1[tid];
  {
    const float4* w4 = (const float4*)(w1 + (size_t)tid * HDIM);
    const float4* h4 = (const float4*)hbuf;
    #pragma unroll 8
    for (int k = 0; k < HDIM / 4; ++k) {
      const float4 wv = w4[k], hv = h4[k];
      acc = fmaf(wv.x, hv.x, acc); acc = fmaf(wv.y, hv.y, acc);
      acc = fmaf(wv.z, hv.z, acc); acc = fmaf(wv.w, hv.w, acc);
    }
  }
  a1[tid] = acc * sigm(acc);
  __syncthreads();

  if (tid < 32) {
    float acc2 = b2[tid];
    #pragma unroll
    for (int k = 0; k < 64; ++k) acc2 = fmaf(a1[k], w2[tid * 64 + k], acc2);
    a2[tid] = acc2 * sigm(acc2);
  }
  __syncthreads();

  if (tid < 16) {
    float acc3 = b3[tid];
    #pragma unroll
    for (int k = 0; k < 32; ++k) acc3 = fmaf(a2[k], w3[tid * 32 + k], acc3);
    out[(size_t)r * 16 + tid] = acc3;
  }
}

// ---------------------------------------------------------------------------
extern "C" void kernel_launch(void* const* d_in, const int* in_sizes, int n_in,
                              void* d_out, int out_size, void* d_ws, size_t ws_size,
                              hipStream_t stream)
{
  (void)in_sizes; (void)n_in; (void)out_size; (void)ws_size;

  const float* x     = (const float*)d_in[0];
  const float* eWih0 = (const float*)d_in[1];
  const float* eWhh0 = (const float*)d_in[2];
  const float* ebih0 = (const float*)d_in[3];
  const float* ebhh0 = (const float*)d_in[4];
  const float* eWih  = (const float*)d_in[5];
  const float* eWhh  = (const float*)d_in[6];
  const float* ebih  = (const float*)d_in[7];
  const float* ebhh  = (const float*)d_in[8];
  const float* dWih  = (const float*)d_in[9];
  const float* dWhh  = (const float*)d_in[10];
  const float* dbih  = (const float*)d_in[11];
  const float* dbhh  = (const float*)d_in[12];
  const float* fc1w  = (const float*)d_in[13];
  const float* fc1b  = (const float*)d_in[14];
  const float* fc2w  = (const float*)d_in[15];
  const float* fc2b  = (const float*)d_in[16];
  const float* fc3w  = (const float*)d_in[17];
  const float* fc3b  = (const float*)d_in[18];
  float* out = (float*)d_out;

  // ws: hring 64KB | xring 2MB | prog 4KB | sout 8MB
  const size_t HB = (size_t)NL * 2 * HDIM * sizeof(unsigned);      // 64 KB
  const size_t XB = (size_t)NL * XRING * HDIM * sizeof(unsigned);  // 2 MB
  Args p{};
  p.x     = x;
  p.hring = (unsigned*)d_ws;
  p.xring = (unsigned*)((char*)d_ws + HB);
  p.prog  = (unsigned*)((char*)d_ws + HB + XB);
  p.sout  = (float*)((char*)d_ws + HB + XB + 4096);

  p.Wih[0] = eWih0; p.Whh[0] = eWhh0; p.bih[0] = ebih0; p.bhh[0] = ebhh0;
  for (int l = 1; l < 8; ++l) {
    p.Wih[l] = eWih + (size_t)(l - 1) * 4 * HDIM * HDIM;
    p.Whh[l] = eWhh + (size_t)(l - 1) * 4 * HDIM * HDIM;
    p.bih[l] = ebih + (size_t)(l - 1) * 4 * HDIM;
    p.bhh[l] = ebhh + (size_t)(l - 1) * 4 * HDIM;
  }
  for (int l = 8; l < 16; ++l) {
    p.Wih[l] = dWih + (size_t)(l - 8) * 4 * HDIM * HDIM;
    p.Whh[l] = dWhh + (size_t)(l - 8) * 4 * HDIM * HDIM;
    p.bih[l] = dbih + (size_t)(l - 8) * 4 * HDIM;
    p.bhh[l] = dbhh + (size_t)(l - 8) * 4 * HDIM;
  }

  // clear ring tags + prog each launch -> replay-safe
  hipMemsetAsync(d_ws, 0, HB + XB + 4096, stream);

  void* args[] = { &p };
  hipError_t e = hipLaunchCooperativeKernel((const void*)lstm16_kernel,
                                            dim3(NL * BPL), dim3(NTH), args, 0,
                                            stream);
  if (e != hipSuccess)   // 256 blocks @ 1/CU on 256 CUs: co-resident anyway
    lstm16_kernel<<<dim3(NL * BPL), dim3(NTH), 0, stream>>>(p);

  mlp_head_kernel<<<dim3(T_SEQ), dim3(64), 0, stream>>>(
      p.sout, fc1w, fc1b, fc2w, fc2b, fc3w, fc3b, out);
}

// Round 8
// 9468.345 us; speedup vs baseline: 1.8025x; 1.5576x over previous
//
#include <hip/hip_runtime.h>
#include <math.h>

// ---------------------------------------------------------------------------
// Fused 16-layer LSTM pipeline (H=512, T=4096) + MLP head.
// EXACT round-4 structure (best verified: 9.24 ms) with ONE change:
//   in-loop barriers are `s_waitcnt lgkmcnt(0); s_barrier` instead of
//   __syncthreads() (which is vmcnt(0) lgkmcnt(0) + s_barrier). The vmcnt(0)
//   drain forced every wave to wait for the 32 sc1 h-post ACKs (~0.4-0.9us
//   MALL RT) inside the step period. Correctness does not need that drain:
//   consumers tag-poll (fire-and-forget visibility), sout/prog are read only
//   after kernel end, and the barriers only order the vh/vx LDS staging --
//   which lgkmcnt(0) covers.
//
//  - 256 blocks = 16 layers x 16 blocks/layer, 1024 thr (16 waves), 1/CU.
//  - Per thread: 1 h-index x 4 gates x 16-k slice, weights f16-packed in
//    64 u32 (register/AGPR-resident; FETCH evidence shows no memory spill).
//  - Ring atoms {tag32 | f32 h} u64, relaxed agent-scope (sc1) loads/stores.
//  - Waves 0-7 poll h; waves 8-15 stage x (one step ahead, parity dbuf).
//  - Posts are PRE-BAR2 (r5 proved moving them after the barrier serializes
//    a compute phase into the h-cycle).
// ---------------------------------------------------------------------------

#define T_SEQ 4096
#define HDIM  512
#define NL    16
#define BPL   16
#define NTH   1024
#define RING  64

typedef unsigned long long u64;
typedef _Float16 half2v __attribute__((ext_vector_type(2)));

struct Args {
  const float* x;
  const float* Wih[NL]; const float* Whh[NL];
  const float* bih[NL]; const float* bhh[NL];
  u64* ring;        // [NL][RING][HDIM] tagged h
  unsigned* prog;   // [(NL+1)*BPL] progress flags
  float* sout;      // [T_SEQ][HDIM]
};

__device__ __forceinline__ u64 aloadU(const u64* p) {
  return __hip_atomic_load(p, __ATOMIC_RELAXED, __HIP_MEMORY_SCOPE_AGENT);
}
__device__ __forceinline__ void astoreU(u64* p, u64 v) {
  __hip_atomic_store(p, v, __ATOMIC_RELAXED, __HIP_MEMORY_SCOPE_AGENT);
}
__device__ __forceinline__ unsigned aloadu(const unsigned* p) {
  return __hip_atomic_load(p, __ATOMIC_RELAXED, __HIP_MEMORY_SCOPE_AGENT);
}
__device__ __forceinline__ float sigm(float x) { return 1.f / (1.f + __expf(-x)); }
__device__ __forceinline__ float tanhx(float x) {
  const float e = __expf(-2.f * fabsf(x));
  return copysignf((1.f - e) / (1.f + e), x);
}

// LDS-only barrier: orders ds_write -> s_barrier -> ds_read without draining
// outstanding global (vmcnt) traffic. sched_barrier fences stop hipcc from
// hoisting memory ops across the asm (guide rule #18).
__device__ __forceinline__ void lds_barrier() {
  __builtin_amdgcn_sched_barrier(0);
  asm volatile("s_waitcnt lgkmcnt(0)\n\ts_barrier" ::: "memory");
  __builtin_amdgcn_sched_barrier(0);
}

#if __has_builtin(__builtin_amdgcn_fdot2)
#define DOT2(w, v, acc) __builtin_amdgcn_fdot2((w), (v), (acc), false)
#else
__device__ __forceinline__ float DOT2(half2v w, half2v v, float acc) {
  return acc + (float)w.x * (float)v.x + (float)w.y * (float)v.y;
}
#endif

#define BC(u) __builtin_bit_cast(half2v, (u))
#define DOTS8(acc, W) \
  acc = DOT2(W[0], p0, acc); acc = DOT2(W[1], p1, acc); \
  acc = DOT2(W[2], p2, acc); acc = DOT2(W[3], p3, acc); \
  acc = DOT2(W[4], p4, acc); acc = DOT2(W[5], p5, acc); \
  acc = DOT2(W[6], p6, acc); acc = DOT2(W[7], p7, acc)

__global__ void __launch_bounds__(NTH) lstm16_kernel(Args a)
{
  const int tid   = threadIdx.x;
  const int layer = blockIdx.x & 15;
  const int b     = blockIdx.x >> 4;
  const int hi    = tid >> 5;          // 0..31: h-index within block
  const int cs    = tid & 31;          // 0..31: k-chunk (16x + 16h floats)
  const int kx    = cs * 16;
  const int hq    = b * 32 + hi;
  const int D     = layer ? HDIM : 128;

  // ---- weights: all 4 gates f16-packed, 64 VGPRs total ----
  half2v wx[4][8], wh[4][8];
  float  bs[4];
  const bool xok = (kx + 16 <= D);
  #pragma unroll
  for (int q = 0; q < 4; ++q) {
    const int row = q * HDIM + hq;
    bs[q] = a.bih[layer][row] + a.bhh[layer][row];
    const float2* px = (const float2*)(a.Wih[layer] + (size_t)row * D + kx);
    const float2* ph = (const float2*)(a.Whh[layer] + (size_t)row * HDIM + kx);
    #pragma unroll
    for (int p = 0; p < 8; ++p) {
      const float2 t0 = xok ? px[p] : make_float2(0.f, 0.f);
      const float2 t1 = ph[p];
      half2v w0; w0.x = (_Float16)t0.x; w0.y = (_Float16)t0.y; wx[q][p] = w0;
      half2v w1; w1.x = (_Float16)t1.x; w1.y = (_Float16)t1.y; wh[q][p] = w1;
    }
  }

  // LDS: x parity-double-buffered, h single (stride 10 u32 -> 2-way = free)
  __shared__ __align__(8) unsigned vx16[2][320];
  __shared__ __align__(8) unsigned vh16[320];

  u64* ringOwn        = a.ring + (size_t)layer * RING * HDIM;
  const u64* ringPrev = a.ring + (size_t)(layer ? layer - 1 : 0) * RING * HDIM;
  const unsigned* progNext = a.prog + (layer + 1) * BPL;
  unsigned* myprog         = a.prog + layer * BPL + b;

  // ---- x staging for step tt into vx16[tt&1] (waves 8-15 only) ----
  auto stage_x = [&](int tt) {
    if (tid < 512) return;
    const int w = tid - 512;
    bool okbp = !((layer < NL - 1) && (w < 16) && ((tt & 7) == 0));
    float xv = 0.f;
    if (layer == 0) {
      if (w < 128) xv = a.x[(size_t)tt * 128 + w];
      if (!okbp)
        while ((int)aloadu(progNext + w) < tt - 40) __builtin_amdgcn_s_sleep(2);
    } else {
      const u64* xw = ringPrev + (size_t)(tt & (RING - 1)) * HDIM + w;
      u64 u = aloadU(xw);
      bool ok = ((unsigned)(u >> 32) == (unsigned)(tt + 1));
      while (!__all(ok & okbp)) {
        if (!ok) {
          u = aloadU(xw);
          ok = ((unsigned)(u >> 32) == (unsigned)(tt + 1));
          if (!ok) __builtin_amdgcn_s_sleep(1);
        }
        if (!okbp) okbp = ((int)aloadu(progNext + w) >= tt - 40);
      }
      xv = __builtin_bit_cast(float, (unsigned)(u & 0xffffffffu));
    }
    const float nb = __shfl_down(xv, 1);
    if (!(w & 1)) {
      half2v pk; pk.x = (_Float16)xv; pk.y = (_Float16)nb;
      vx16[tt & 1][(w >> 4) * 10 + ((w & 15) >> 1)] =
          __builtin_bit_cast(unsigned, pk);
    }
  };

  stage_x(0);
  __syncthreads();   // cold prologue barrier: full sync is fine here

  float c_state = 0.f;   // lanes cs==0 own h-index hq

  for (int t = 0; t < T_SEQ; ++t) {
    // ---- issue h tagged-load early (waves 0-7; hides under x-dots) ----
    u64 hu = 0; const u64* hw = ringOwn;
    const bool hpoll = (t > 0) && (tid < 512);
    if (hpoll) {
      hw = ringOwn + (size_t)((t - 1) & (RING - 1)) * HDIM + tid;
      hu = aloadU(hw);
    }

    // ---- x-dots from vx16[t&1] (staged last iteration) ----
    float a0 = 0.f, a1 = 0.f, a2 = 0.f, a3 = 0.f;
    {
      const unsigned* vb = vx16[t & 1] + cs * 10;
      const uint2 u0 = *(const uint2*)(vb + 0);
      const uint2 u1 = *(const uint2*)(vb + 2);
      const uint2 u2 = *(const uint2*)(vb + 4);
      const uint2 u3 = *(const uint2*)(vb + 6);
      const half2v p0 = BC(u0.x), p1 = BC(u0.y), p2 = BC(u1.x), p3 = BC(u1.y);
      const half2v p4 = BC(u2.x), p5 = BC(u2.y), p6 = BC(u3.x), p7 = BC(u3.y);
      DOTS8(a0, wx[0]); DOTS8(a1, wx[1]); DOTS8(a2, wx[2]); DOTS8(a3, wx[3]);
    }

    // ---- h: finish poll, stage, dots ----
    if (t > 0) {
      if (tid < 512) {
        bool ok = ((unsigned)(hu >> 32) == (unsigned)t);
        while (!__all(ok)) {
          if (!ok) { hu = aloadU(hw); ok = ((unsigned)(hu >> 32) == (unsigned)t); }
        }
        const float hv = __builtin_bit_cast(float, (unsigned)(hu & 0xffffffffu));
        const float nb = __shfl_down(hv, 1);
        if (!(tid & 1)) {
          half2v pk; pk.x = (_Float16)hv; pk.y = (_Float16)nb;
          vh16[(tid >> 4) * 10 + ((tid & 15) >> 1)] =
              __builtin_bit_cast(unsigned, pk);
        }
      }
      lds_barrier();   // BAR1: vh staged (LDS-only; no vmcnt drain)
      {
        const unsigned* vb = vh16 + cs * 10;
        const uint2 u0 = *(const uint2*)(vb + 0);
        const uint2 u1 = *(const uint2*)(vb + 2);
        const uint2 u2 = *(const uint2*)(vb + 4);
        const uint2 u3 = *(const uint2*)(vb + 6);
        const half2v p0 = BC(u0.x), p1 = BC(u0.y), p2 = BC(u1.x), p3 = BC(u1.y);
        const half2v p4 = BC(u2.x), p5 = BC(u2.y), p6 = BC(u3.x), p7 = BC(u3.y);
        DOTS8(a0, wh[0]); DOTS8(a1, wh[1]); DOTS8(a2, wh[2]); DOTS8(a3, wh[3]);
      }
    }

    // ---- reduce across 32 k-lanes (stays within 32-lane halves) ----
    #pragma unroll
    for (int d = 1; d < 32; d <<= 1) {
      a0 += __shfl_xor(a0, d); a1 += __shfl_xor(a1, d);
      a2 += __shfl_xor(a2, d); a3 += __shfl_xor(a3, d);
    }

    // ---- gates + post (lanes cs==0: one per h-index; pre-BAR2) ----
    if (cs == 0) {
      const float gi = sigm(a0 + bs[0]);
      const float gf = sigm(a1 + bs[1]);
      const float gg = tanhx(a2 + bs[2]);
      const float go = sigm(a3 + bs[3]);
      c_state = gf * c_state + gi * gg;
      const float h = go * tanhx(c_state);
      astoreU(ringOwn + (size_t)(t & (RING - 1)) * HDIM + hq,
              ((u64)(unsigned)(t + 1) << 32) | (u64)__builtin_bit_cast(unsigned, h));
      if (layer == NL - 1) a.sout[(size_t)t * HDIM + hq] = h;
    }
    if (tid == 0 && (t & 7) == 7)
      __hip_atomic_store(myprog, (unsigned)(t + 1), __ATOMIC_RELAXED,
                         __HIP_MEMORY_SCOPE_AGENT);

    // ---- prefetch x_{t+1} (slack path, waves 8-15) ----
    if (t + 1 < T_SEQ) stage_x(t + 1);
    lds_barrier();   // BAR2: vx staged (LDS-only; posts fly async)
  }
}

// ---------------- MLP head: (T,512) -> 64 -> 32 -> 16 ----------------
__global__ void __launch_bounds__(64) mlp_head_kernel(
    const float* __restrict__ S,
    const float* __restrict__ w1, const float* __restrict__ b1,
    const float* __restrict__ w2, const float* __restrict__ b2,
    const float* __restrict__ w3, const float* __restrict__ b3,
    float* __restrict__ out)
{
  const int r   = blockIdx.x;
  const int tid = threadIdx.x;
  __shared__ __align__(16) float hbuf[HDIM];
  __shared__ float a1[64];
  __shared__ float a2[32];

  #pragma unroll
  for (int u = 0; u < HDIM / 64; ++u)
    hbuf[u * 64 + tid] = S[(size_t)r * HDIM + u * 64 + tid];
  __syncthreads();

  float acc = b1[tid];
  {
    const float4* w4 = (const float4*)(w1 + (size_t)tid * HDIM);
    const float4* h4 = (const float4*)hbuf;
    #pragma unroll 8
    for (int k = 0; k < HDIM / 4; ++k) {
      const float4 wv = w4[k], hv = h4[k];
      acc = fmaf(wv.x, hv.x, acc); acc = fmaf(wv.y, hv.y, acc);
      acc = fmaf(wv.z, hv.z, acc); acc = fmaf(wv.w, hv.w, acc);
    }
  }
  a1[tid] = acc * sigm(acc);
  __syncthreads();

  if (tid < 32) {
    float acc2 = b2[tid];
    #pragma unroll
    for (int k = 0; k < 64; ++k) acc2 = fmaf(a1[k], w2[tid * 64 + k], acc2);
    a2[tid] = acc2 * sigm(acc2);
  }
  __syncthreads();

  if (tid < 16) {
    float acc3 = b3[tid];
    #pragma unroll
    for (int k = 0; k < 32; ++k) acc3 = fmaf(a2[k], w3[tid * 32 + k], acc3);
    out[(size_t)r * 16 + tid] = acc3;
  }
}

// ---------------------------------------------------------------------------
extern "C" void kernel_launch(void* const* d_in, const int* in_sizes, int n_in,
                              void* d_out, int out_size, void* d_ws, size_t ws_size,
                              hipStream_t stream)
{
  (void)in_sizes; (void)n_in; (void)out_size; (void)ws_size;

  const float* x     = (const float*)d_in[0];
  const float* eWih0 = (const float*)d_in[1];
  const float* eWhh0 = (const float*)d_in[2];
  const float* ebih0 = (const float*)d_in[3];
  const float* ebhh0 = (const float*)d_in[4];
  const float* eWih  = (const float*)d_in[5];
  const float* eWhh  = (const float*)d_in[6];
  const float* ebih  = (const float*)d_in[7];
  const float* ebhh  = (const float*)d_in[8];
  const float* dWih  = (const float*)d_in[9];
  const float* dWhh  = (const float*)d_in[10];
  const float* dbih  = (const float*)d_in[11];
  const float* dbhh  = (const float*)d_in[12];
  const float* fc1w  = (const float*)d_in[13];
  const float* fc1b  = (const float*)d_in[14];
  const float* fc2w  = (const float*)d_in[15];
  const float* fc2b  = (const float*)d_in[16];
  const float* fc3w  = (const float*)d_in[17];
  const float* fc3b  = (const float*)d_in[18];
  float* out = (float*)d_out;

  // ws layout: ring 4 MB | prog (4 KB) | sout 8 MB
  const size_t RINGBYTES = (size_t)NL * RING * HDIM * sizeof(u64);  // 4 MB
  Args p{};
  p.x    = x;
  p.ring = (u64*)d_ws;
  p.prog = (unsigned*)((char*)d_ws + RINGBYTES);
  p.sout = (float*)((char*)d_ws + RINGBYTES + 4096);

  p.Wih[0] = eWih0; p.Whh[0] = eWhh0; p.bih[0] = ebih0; p.bhh[0] = ebhh0;
  for (int l = 1; l < 8; ++l) {
    p.Wih[l] = eWih + (size_t)(l - 1) * 4 * HDIM * HDIM;
    p.Whh[l] = eWhh + (size_t)(l - 1) * 4 * HDIM * HDIM;
    p.bih[l] = ebih + (size_t)(l - 1) * 4 * HDIM;
    p.bhh[l] = ebhh + (size_t)(l - 1) * 4 * HDIM;
  }
  for (int l = 8; l < 16; ++l) {
    p.Wih[l] = dWih + (size_t)(l - 8) * 4 * HDIM * HDIM;
    p.Whh[l] = dWhh + (size_t)(l - 8) * 4 * HDIM * HDIM;
    p.bih[l] = dbih + (size_t)(l - 8) * 4 * HDIM;
    p.bhh[l] = dbhh + (size_t)(l - 8) * 4 * HDIM;
  }

  // clear rings (tags) + progress flags each launch -> replay-safe
  hipMemsetAsync(d_ws, 0, RINGBYTES + 4096, stream);

  void* args[] = { &p };
  hipError_t e = hipLaunchCooperativeKernel((const void*)lstm16_kernel,
                                            dim3(NL * BPL), dim3(NTH), args, 0,
                                            stream);
  if (e != hipSuccess)   // 256 blocks @ 1/CU on 256 CUs: co-resident anyway
    lstm16_kernel<<<dim3(NL * BPL), dim3(NTH), 0, stream>>>(p);

  mlp_head_kernel<<<dim3(T_SEQ), dim3(64), 0, stream>>>(
      p.sout, fc1w, fc1b, fc2w, fc2b, fc3w, fc3b, out);
}

// Round 9
// 9377.608 us; speedup vs baseline: 1.8199x; 1.0097x over previous
//
#include <hip/hip_runtime.h>
#include <math.h>

// ---------------------------------------------------------------------------
// Fused 16-layer LSTM pipeline (H=512, T=4096) + MLP head.
// EXACT round-4 structure (best verified: 9.24 ms) with ONE change:
//   the 32-lane accumulator reduce uses DPP (v_add_f32 row_shr:1/2/4/8 +
//   row_bcast:15 with row_mask 0xa) instead of 20 ds_swizzle shuffles.
//   r4 burned 320 DS-pipe issues per block-step (16 waves x 20) on the
//   critical path between h-arrival and h-post; DPP moves the reduce to
//   the VALU (5 dependent adds, ~135ns). Totals land on lanes 31/63 of
//   each wave -> gate/post lane role is cs==31 (was cs==0).
//
//  - 256 blocks = 16 layers x 16 blocks/layer, 1024 thr (16 waves), 1/CU.
//  - Per thread: 1 h-index x 4 gates x 16-k slice, weights f16-packed in
//    64 u32. fp32 accumulate via v_dot2_f32_f16.
//  - Ring atoms {tag32 | f32 h} u64, relaxed agent-scope (sc1) — the proven
//    visibility path (r6's sc0 experiment deadlocked; never again).
//  - Waves 0-7 poll h; waves 8-15 stage x one step ahead (parity dbuf).
//  - Posts PRE-BAR2 (r5 proved the ordering is load-bearing).
// ---------------------------------------------------------------------------

#define T_SEQ 4096
#define HDIM  512
#define NL    16
#define BPL   16
#define NTH   1024
#define RING  64

typedef unsigned long long u64;
typedef _Float16 half2v __attribute__((ext_vector_type(2)));

struct Args {
  const float* x;
  const float* Wih[NL]; const float* Whh[NL];
  const float* bih[NL]; const float* bhh[NL];
  u64* ring;        // [NL][RING][HDIM] tagged h
  unsigned* prog;   // [(NL+1)*BPL] progress flags
  float* sout;      // [T_SEQ][HDIM]
};

__device__ __forceinline__ u64 aloadU(const u64* p) {
  return __hip_atomic_load(p, __ATOMIC_RELAXED, __HIP_MEMORY_SCOPE_AGENT);
}
__device__ __forceinline__ void astoreU(u64* p, u64 v) {
  __hip_atomic_store(p, v, __ATOMIC_RELAXED, __HIP_MEMORY_SCOPE_AGENT);
}
__device__ __forceinline__ unsigned aloadu(const unsigned* p) {
  return __hip_atomic_load(p, __ATOMIC_RELAXED, __HIP_MEMORY_SCOPE_AGENT);
}
__device__ __forceinline__ float sigm(float x) { return 1.f / (1.f + __expf(-x)); }
__device__ __forceinline__ float tanhx(float x) {
  const float e = __expf(-2.f * fabsf(x));
  return copysignf((1.f - e) / (1.f + e), x);
}

#if __has_builtin(__builtin_amdgcn_fdot2)
#define DOT2(w, v, acc) __builtin_amdgcn_fdot2((w), (v), (acc), false)
#else
__device__ __forceinline__ float DOT2(half2v w, half2v v, float acc) {
  return acc + (float)w.x * (float)v.x + (float)w.y * (float)v.y;
}
#endif

// 32-lane-group sum via DPP. After row_shr 1/2/4/8 each row-of-16's lane15
// (lanes 15,31,47,63) holds that row's sum; row_bcast:15 with row_mask 0xa
// adds it into rows 1,3 only (no cross-group leak) -> lanes 31 and 63 hold
// their 32-group totals.
#if __has_builtin(__builtin_amdgcn_update_dpp)
template <int CTRL, int RMASK>
__device__ __forceinline__ float dpp_add(float a) {
  const int t = __builtin_amdgcn_update_dpp(
      0, __builtin_bit_cast(int, a), CTRL, RMASK, 0xf, true);
  return a + __builtin_bit_cast(float, t);
}
#define REDUCE32(v)                                          \
  v = dpp_add<0x111, 0xf>(v); v = dpp_add<0x112, 0xf>(v);    \
  v = dpp_add<0x114, 0xf>(v); v = dpp_add<0x118, 0xf>(v);    \
  v = dpp_add<0x142, 0xa>(v)
#else
#define REDUCE32(v)                                          \
  { _Pragma("unroll")                                        \
    for (int d = 1; d < 32; d <<= 1) v += __shfl_xor(v, d); }
#endif

#define BC(u) __builtin_bit_cast(half2v, (u))
#define DOTS8(acc, W) \
  acc = DOT2(W[0], p0, acc); acc = DOT2(W[1], p1, acc); \
  acc = DOT2(W[2], p2, acc); acc = DOT2(W[3], p3, acc); \
  acc = DOT2(W[4], p4, acc); acc = DOT2(W[5], p5, acc); \
  acc = DOT2(W[6], p6, acc); acc = DOT2(W[7], p7, acc)

__global__ void __launch_bounds__(NTH) lstm16_kernel(Args a)
{
  const int tid   = threadIdx.x;
  const int layer = blockIdx.x & 15;
  const int b     = blockIdx.x >> 4;
  const int hi    = tid >> 5;          // 0..31: h-index within block
  const int cs    = tid & 31;          // 0..31: k-chunk (16x + 16h floats)
  const int kx    = cs * 16;
  const int hq    = b * 32 + hi;
  const int D     = layer ? HDIM : 128;

  // ---- weights: all 4 gates f16-packed, 64 VGPRs total ----
  half2v wx[4][8], wh[4][8];
  float  bs[4];
  const bool xok = (kx + 16 <= D);
  #pragma unroll
  for (int q = 0; q < 4; ++q) {
    const int row = q * HDIM + hq;
    bs[q] = a.bih[layer][row] + a.bhh[layer][row];
    const float2* px = (const float2*)(a.Wih[layer] + (size_t)row * D + kx);
    const float2* ph = (const float2*)(a.Whh[layer] + (size_t)row * HDIM + kx);
    #pragma unroll
    for (int p = 0; p < 8; ++p) {
      const float2 t0 = xok ? px[p] : make_float2(0.f, 0.f);
      const float2 t1 = ph[p];
      half2v w0; w0.x = (_Float16)t0.x; w0.y = (_Float16)t0.y; wx[q][p] = w0;
      half2v w1; w1.x = (_Float16)t1.x; w1.y = (_Float16)t1.y; wh[q][p] = w1;
    }
  }

  // LDS: x parity-double-buffered, h single (stride 10 u32 -> 2-way = free)
  __shared__ __align__(8) unsigned vx16[2][320];
  __shared__ __align__(8) unsigned vh16[320];

  u64* ringOwn        = a.ring + (size_t)layer * RING * HDIM;
  const u64* ringPrev = a.ring + (size_t)(layer ? layer - 1 : 0) * RING * HDIM;
  const unsigned* progNext = a.prog + (layer + 1) * BPL;
  unsigned* myprog         = a.prog + layer * BPL + b;

  // ---- x staging for step tt into vx16[tt&1] (waves 8-15 only) ----
  auto stage_x = [&](int tt) {
    if (tid < 512) return;
    const int w = tid - 512;
    bool okbp = !((layer < NL - 1) && (w < 16) && ((tt & 7) == 0));
    float xv = 0.f;
    if (layer == 0) {
      if (w < 128) xv = a.x[(size_t)tt * 128 + w];
      if (!okbp)
        while ((int)aloadu(progNext + w) < tt - 40) __builtin_amdgcn_s_sleep(2);
    } else {
      const u64* xw = ringPrev + (size_t)(tt & (RING - 1)) * HDIM + w;
      u64 u = aloadU(xw);
      bool ok = ((unsigned)(u >> 32) == (unsigned)(tt + 1));
      while (!__all(ok & okbp)) {
        if (!ok) {
          u = aloadU(xw);
          ok = ((unsigned)(u >> 32) == (unsigned)(tt + 1));
          if (!ok) __builtin_amdgcn_s_sleep(1);
        }
        if (!okbp) okbp = ((int)aloadu(progNext + w) >= tt - 40);
      }
      xv = __builtin_bit_cast(float, (unsigned)(u & 0xffffffffu));
    }
    const float nb = __shfl_down(xv, 1);
    if (!(w & 1)) {
      half2v pk; pk.x = (_Float16)xv; pk.y = (_Float16)nb;
      vx16[tt & 1][(w >> 4) * 10 + ((w & 15) >> 1)] =
          __builtin_bit_cast(unsigned, pk);
    }
  };

  stage_x(0);
  __syncthreads();

  float c_state = 0.f;   // lanes cs==31 own h-index hq

  for (int t = 0; t < T_SEQ; ++t) {
    // ---- issue h tagged-load early (waves 0-7; hides under x-dots) ----
    u64 hu = 0; const u64* hw = ringOwn;
    const bool hpoll = (t > 0) && (tid < 512);
    if (hpoll) {
      hw = ringOwn + (size_t)((t - 1) & (RING - 1)) * HDIM + tid;
      hu = aloadU(hw);
    }

    // ---- x-dots from vx16[t&1] (staged last iteration) ----
    float a0 = 0.f, a1 = 0.f, a2 = 0.f, a3 = 0.f;
    {
      const unsigned* vb = vx16[t & 1] + cs * 10;
      const uint2 u0 = *(const uint2*)(vb + 0);
      const uint2 u1 = *(const uint2*)(vb + 2);
      const uint2 u2 = *(const uint2*)(vb + 4);
      const uint2 u3 = *(const uint2*)(vb + 6);
      const half2v p0 = BC(u0.x), p1 = BC(u0.y), p2 = BC(u1.x), p3 = BC(u1.y);
      const half2v p4 = BC(u2.x), p5 = BC(u2.y), p6 = BC(u3.x), p7 = BC(u3.y);
      DOTS8(a0, wx[0]); DOTS8(a1, wx[1]); DOTS8(a2, wx[2]); DOTS8(a3, wx[3]);
    }

    // ---- h: finish poll, stage, dots ----
    if (t > 0) {
      if (tid < 512) {
        bool ok = ((unsigned)(hu >> 32) == (unsigned)t);
        while (!__all(ok)) {
          if (!ok) { hu = aloadU(hw); ok = ((unsigned)(hu >> 32) == (unsigned)t); }
        }
        const float hv = __builtin_bit_cast(float, (unsigned)(hu & 0xffffffffu));
        const float nb = __shfl_down(hv, 1);
        if (!(tid & 1)) {
          half2v pk; pk.x = (_Float16)hv; pk.y = (_Float16)nb;
          vh16[(tid >> 4) * 10 + ((tid & 15) >> 1)] =
              __builtin_bit_cast(unsigned, pk);
        }
      }
      __syncthreads();   // BAR1: vh staged
      {
        const unsigned* vb = vh16 + cs * 10;
        const uint2 u0 = *(const uint2*)(vb + 0);
        const uint2 u1 = *(const uint2*)(vb + 2);
        const uint2 u2 = *(const uint2*)(vb + 4);
        const uint2 u3 = *(const uint2*)(vb + 6);
        const half2v p0 = BC(u0.x), p1 = BC(u0.y), p2 = BC(u1.x), p3 = BC(u1.y);
        const half2v p4 = BC(u2.x), p5 = BC(u2.y), p6 = BC(u3.x), p7 = BC(u3.y);
        DOTS8(a0, wh[0]); DOTS8(a1, wh[1]); DOTS8(a2, wh[2]); DOTS8(a3, wh[3]);
      }
    }

    // ---- reduce across 32 k-lanes: DPP (VALU), totals on lanes 31/63 ----
    REDUCE32(a0); REDUCE32(a1); REDUCE32(a2); REDUCE32(a3);

    // ---- gates + post (lanes cs==31: one per h-index; pre-BAR2) ----
    if (cs == 31) {
      const float gi = sigm(a0 + bs[0]);
      const float gf = sigm(a1 + bs[1]);
      const float gg = tanhx(a2 + bs[2]);
      const float go = sigm(a3 + bs[3]);
      c_state = gf * c_state + gi * gg;
      const float h = go * tanhx(c_state);
      astoreU(ringOwn + (size_t)(t & (RING - 1)) * HDIM + hq,
              ((u64)(unsigned)(t + 1) << 32) | (u64)__builtin_bit_cast(unsigned, h));
      if (layer == NL - 1) a.sout[(size_t)t * HDIM + hq] = h;
    }
    if (tid == 0 && (t & 7) == 7)
      __hip_atomic_store(myprog, (unsigned)(t + 1), __ATOMIC_RELAXED,
                         __HIP_MEMORY_SCOPE_AGENT);

    // ---- prefetch x_{t+1} (slack path, waves 8-15) ----
    if (t + 1 < T_SEQ) stage_x(t + 1);
    __syncthreads();     // BAR2
  }
}

// ---------------- MLP head: (T,512) -> 64 -> 32 -> 16 ----------------
__global__ void __launch_bounds__(64) mlp_head_kernel(
    const float* __restrict__ S,
    const float* __restrict__ w1, const float* __restrict__ b1,
    const float* __restrict__ w2, const float* __restrict__ b2,
    const float* __restrict__ w3, const float* __restrict__ b3,
    float* __restrict__ out)
{
  const int r   = blockIdx.x;
  const int tid = threadIdx.x;
  __shared__ __align__(16) float hbuf[HDIM];
  __shared__ float a1[64];
  __shared__ float a2[32];

  #pragma unroll
  for (int u = 0; u < HDIM / 64; ++u)
    hbuf[u * 64 + tid] = S[(size_t)r * HDIM + u * 64 + tid];
  __syncthreads();

  float acc = b1[tid];
  {
    const float4* w4 = (const float4*)(w1 + (size_t)tid * HDIM);
    const float4* h4 = (const float4*)hbuf;
    #pragma unroll 8
    for (int k = 0; k < HDIM / 4; ++k) {
      const float4 wv = w4[k], hv = h4[k];
      acc = fmaf(wv.x, hv.x, acc); acc = fmaf(wv.y, hv.y, acc);
      acc = fmaf(wv.z, hv.z, acc); acc = fmaf(wv.w, hv.w, acc);
    }
  }
  a1[tid] = acc * sigm(acc);
  __syncthreads();

  if (tid < 32) {
    float acc2 = b2[tid];
    #pragma unroll
    for (int k = 0; k < 64; ++k) acc2 = fmaf(a1[k], w2[tid * 64 + k], acc2);
    a2[tid] = acc2 * sigm(acc2);
  }
  __syncthreads();

  if (tid < 16) {
    float acc3 = b3[tid];
    #pragma unroll
    for (int k = 0; k < 32; ++k) acc3 = fmaf(a2[k], w3[tid * 32 + k], acc3);
    out[(size_t)r * 16 + tid] = acc3;
  }
}

// ---------------------------------------------------------------------------
extern "C" void kernel_launch(void* const* d_in, const int* in_sizes, int n_in,
                              void* d_out, int out_size, void* d_ws, size_t ws_size,
                              hipStream_t stream)
{
  (void)in_sizes; (void)n_in; (void)out_size; (void)ws_size;

  const float* x     = (const float*)d_in[0];
  const float* eWih0 = (const float*)d_in[1];
  const float* eWhh0 = (const float*)d_in[2];
  const float* ebih0 = (const float*)d_in[3];
  const float* ebhh0 = (const float*)d_in[4];
  const float* eWih  = (const float*)d_in[5];
  const float* eWhh  = (const float*)d_in[6];
  const float* ebih  = (const float*)d_in[7];
  const float* ebhh  = (const float*)d_in[8];
  const float* dWih  = (const float*)d_in[9];
  const float* dWhh  = (const float*)d_in[10];
  const float* dbih  = (const float*)d_in[11];
  const float* dbhh  = (const float*)d_in[12];
  const float* fc1w  = (const float*)d_in[13];
  const float* fc1b  = (const float*)d_in[14];
  const float* fc2w  = (const float*)d_in[15];
  const float* fc2b  = (const float*)d_in[16];
  const float* fc3w  = (const float*)d_in[17];
  const float* fc3b  = (const float*)d_in[18];
  float* out = (float*)d_out;

  // ws layout: ring 4 MB | prog (4 KB) | sout 8 MB
  const size_t RINGBYTES = (size_t)NL * RING * HDIM * sizeof(u64);  // 4 MB
  Args p{};
  p.x    = x;
  p.ring = (u64*)d_ws;
  p.prog = (unsigned*)((char*)d_ws + RINGBYTES);
  p.sout = (float*)((char*)d_ws + RINGBYTES + 4096);

  p.Wih[0] = eWih0; p.Whh[0] = eWhh0; p.bih[0] = ebih0; p.bhh[0] = ebhh0;
  for (int l = 1; l < 8; ++l) {
    p.Wih[l] = eWih + (size_t)(l - 1) * 4 * HDIM * HDIM;
    p.Whh[l] = eWhh + (size_t)(l - 1) * 4 * HDIM * HDIM;
    p.bih[l] = ebih + (size_t)(l - 1) * 4 * HDIM;
    p.bhh[l] = ebhh + (size_t)(l - 1) * 4 * HDIM;
  }
  for (int l = 8; l < 16; ++l) {
    p.Wih[l] = dWih + (size_t)(l - 8) * 4 * HDIM * HDIM;
    p.Whh[l] = dWhh + (size_t)(l - 8) * 4 * HDIM * HDIM;
    p.bih[l] = dbih + (size_t)(l - 8) * 4 * HDIM;
    p.bhh[l] = dbhh + (size_t)(l - 8) * 4 * HDIM;
  }

  // clear rings (tags) + progress flags each launch -> replay-safe
  hipMemsetAsync(d_ws, 0, RINGBYTES + 4096, stream);

  void* args[] = { &p };
  hipError_t e = hipLaunchCooperativeKernel((const void*)lstm16_kernel,
                                            dim3(NL * BPL), dim3(NTH), args, 0,
                                            stream);
  if (e != hipSuccess)   // 256 blocks @ 1/CU on 256 CUs: co-resident anyway
    lstm16_kernel<<<dim3(NL * BPL), dim3(NTH), 0, stream>>>(p);

  mlp_head_kernel<<<dim3(T_SEQ), dim3(64), 0, stream>>>(
      p.sout, fc1w, fc1b, fc2w, fc2b, fc3w, fc3b, out);
}

// Round 11
// 9339.851 us; speedup vs baseline: 1.8273x; 1.0040x over previous
//
#include <hip/hip_runtime.h>
#include <math.h>

// ---------------------------------------------------------------------------
// Fused 16-layer LSTM pipeline (H=512, T=4096) + MLP head.
// Round-4 structure (best verified: 9.24 ms) + three poll-path changes:
//  (1) h-poll narrowed: 256 lanes (waves 0-3) load dwordx4 = 2 tagged ring
//      words each (single 64B-line snapshot; both tags checked). Halves the
//      spin request rate and the number of spinning waves.
//  (2) s_sleep(1) backoff in the h-spin (r4 had none -> ~4 TB/s poll storm
//      at the MALL; self-congesting). Costs <=64cyc detection if uncongested.
//  (3) T14 async x-split: x(t+1) ring loads ISSUE at iteration top (waves
//      8-15), tag-check + LDS stage at the bottom. Removes a serial MALL RT
//      (r4 issued the x load between post and BAR2 -> on-period).
// r10 fix: HP_WAIT had a tied uint4 "+v" operand (unsupported). Now a bare
// s_waitcnt vmcnt(0) with "memory" clobber + sched_barrier(0) (rule #18:
// the sched_barrier stops hipcc hoisting the register-only tag check above
// the wait).
// Everything else identical to r4: 256 blocks = 16 layers x 16, 1024 thr,
// weights f16-packed in 64 u32/thread, u64 {tag32|f32 h} ring atoms sc1,
// posts PRE-BAR2 (r5: load-bearing), shuffle reduce (r9: DPP neutral).
// ---------------------------------------------------------------------------

#define T_SEQ 4096
#define HDIM  512
#define NL    16
#define BPL   16
#define NTH   1024
#define RING  64

typedef unsigned long long u64;
typedef _Float16 half2v __attribute__((ext_vector_type(2)));

struct Args {
  const float* x;
  const float* Wih[NL]; const float* Whh[NL];
  const float* bih[NL]; const float* bhh[NL];
  u64* ring;        // [NL][RING][HDIM] tagged h
  unsigned* prog;   // [(NL+1)*BPL] progress flags
  float* sout;      // [T_SEQ][HDIM]
};

__device__ __forceinline__ u64 aloadU(const u64* p) {
  return __hip_atomic_load(p, __ATOMIC_RELAXED, __HIP_MEMORY_SCOPE_AGENT);
}
__device__ __forceinline__ void astoreU(u64* p, u64 v) {
  __hip_atomic_store(p, v, __ATOMIC_RELAXED, __HIP_MEMORY_SCOPE_AGENT);
}
__device__ __forceinline__ unsigned aloadu(const unsigned* p) {
  return __hip_atomic_load(p, __ATOMIC_RELAXED, __HIP_MEMORY_SCOPE_AGENT);
}
__device__ __forceinline__ float sigm(float x) { return 1.f / (1.f + __expf(-x)); }
__device__ __forceinline__ float tanhx(float x) {
  const float e = __expf(-2.f * fabsf(x));
  return copysignf((1.f - e) / (1.f + e), x);
}

// Device-scope (sc1) 16B poll primitives. Issue and wait are split so the
// first load's RT hides under the x-dots. The wait is a bare waitcnt with
// "memory" clobber; the sched_barrier(0) after it stops the register-only
// tag check from being hoisted above the wait (guide rule #18).
#define HP_ISSUE(r, p) \
  asm volatile("global_load_dwordx4 %0, %1, off sc1" : "=v"(r) : "v"(p))
#define HP_WAIT()                                          \
  do {                                                     \
    asm volatile("s_waitcnt vmcnt(0)" ::: "memory");       \
    __builtin_amdgcn_sched_barrier(0);                     \
  } while (0)

#if __has_builtin(__builtin_amdgcn_fdot2)
#define DOT2(w, v, acc) __builtin_amdgcn_fdot2((w), (v), (acc), false)
#else
__device__ __forceinline__ float DOT2(half2v w, half2v v, float acc) {
  return acc + (float)w.x * (float)v.x + (float)w.y * (float)v.y;
}
#endif

#define BC(u) __builtin_bit_cast(half2v, (u))
#define DOTS8(acc, W) \
  acc = DOT2(W[0], p0, acc); acc = DOT2(W[1], p1, acc); \
  acc = DOT2(W[2], p2, acc); acc = DOT2(W[3], p3, acc); \
  acc = DOT2(W[4], p4, acc); acc = DOT2(W[5], p5, acc); \
  acc = DOT2(W[6], p6, acc); acc = DOT2(W[7], p7, acc)

__global__ void __launch_bounds__(NTH) lstm16_kernel(Args a)
{
  const int tid   = threadIdx.x;
  const int layer = blockIdx.x & 15;
  const int b     = blockIdx.x >> 4;
  const int hi    = tid >> 5;          // 0..31: h-index within block
  const int cs    = tid & 31;          // 0..31: k-chunk (16x + 16h floats)
  const int kx    = cs * 16;
  const int hq    = b * 32 + hi;
  const int D     = layer ? HDIM : 128;

  // ---- weights: all 4 gates f16-packed, 64 VGPRs total ----
  half2v wx[4][8], wh[4][8];
  float  bs[4];
  const bool xok = (kx + 16 <= D);
  #pragma unroll
  for (int q = 0; q < 4; ++q) {
    const int row = q * HDIM + hq;
    bs[q] = a.bih[layer][row] + a.bhh[layer][row];
    const float2* px = (const float2*)(a.Wih[layer] + (size_t)row * D + kx);
    const float2* ph = (const float2*)(a.Whh[layer] + (size_t)row * HDIM + kx);
    #pragma unroll
    for (int p = 0; p < 8; ++p) {
      const float2 t0 = xok ? px[p] : make_float2(0.f, 0.f);
      const float2 t1 = ph[p];
      half2v w0; w0.x = (_Float16)t0.x; w0.y = (_Float16)t0.y; wx[q][p] = w0;
      half2v w1; w1.x = (_Float16)t1.x; w1.y = (_Float16)t1.y; wh[q][p] = w1;
    }
  }

  // LDS: x parity-double-buffered, h single (stride 10 u32 -> 2-way = free)
  __shared__ __align__(8) unsigned vx16[2][320];
  __shared__ __align__(8) unsigned vh16[320];

  u64* ringOwn        = a.ring + (size_t)layer * RING * HDIM;
  const u64* ringPrev = a.ring + (size_t)(layer ? layer - 1 : 0) * RING * HDIM;
  const unsigned* progNext = a.prog + (layer + 1) * BPL;
  unsigned* myprog         = a.prog + layer * BPL + b;

  // ---- prologue-only full x staging for step 0 (waves 8-15) ----
  auto stage_x0 = [&]() {
    if (tid < 512) return;
    const int w = tid - 512;
    float xv = 0.f;
    if (layer == 0) {
      if (w < 128) xv = a.x[w];
    } else {
      const u64* xw = ringPrev + w;
      u64 u = aloadU(xw);
      bool ok = ((unsigned)(u >> 32) == 1u);
      while (!__all(ok)) {
        if (!ok) {
          u = aloadU(xw);
          ok = ((unsigned)(u >> 32) == 1u);
          if (!ok) __builtin_amdgcn_s_sleep(1);
        }
      }
      xv = __builtin_bit_cast(float, (unsigned)(u & 0xffffffffu));
    }
    const float nb = __shfl_down(xv, 1);
    if (!(w & 1)) {
      half2v pk; pk.x = (_Float16)xv; pk.y = (_Float16)nb;
      vx16[0][(w >> 4) * 10 + ((w & 15) >> 1)] = __builtin_bit_cast(unsigned, pk);
    }
  };

  stage_x0();
  __syncthreads();

  float c_state = 0.f;   // lanes cs==0 own h-index hq

  for (int t = 0; t < T_SEQ; ++t) {
    // ---- (1) issue h(t-1) 16B poll load (waves 0-3; hides under x-dots) ----
    uint4 raw = make_uint4(0, 0, 0, 0);
    const bool hpoll = (t > 0) && (tid < 256);
    const uint4* hw4 =
        (const uint4*)(ringOwn + (size_t)((t - 1) & (RING - 1)) * HDIM) + tid;
    if (hpoll) HP_ISSUE(raw, hw4);

    // ---- (3) issue x(t+1) ring load (waves 8-15; finish at bottom) ----
    u64 xu = 0; const u64* xw = ringPrev;
    float xv0 = 0.f;
    const bool xio = (tid >= 512) && (t + 1 < T_SEQ);
    if (xio) {
      const int w = tid - 512;
      if (layer == 0) {
        if (w < 128) xv0 = a.x[(size_t)(t + 1) * 128 + w];
      } else {
        xw = ringPrev + (size_t)((t + 1) & (RING - 1)) * HDIM + w;
        xu = aloadU(xw);   // compiler schedules the wait at first use (bottom)
      }
      // backpressure check (slack phase, 1/8 steps, 16 lanes)
      if ((layer < NL - 1) && (w < 16) && (((t + 1) & 7) == 0))
        while ((int)aloadu(progNext + w) < t + 1 - 40)
          __builtin_amdgcn_s_sleep(2);
    }

    // ---- x-dots from vx16[t&1] (staged last iteration) ----
    float a0 = 0.f, a1 = 0.f, a2 = 0.f, a3 = 0.f;
    {
      const unsigned* vb = vx16[t & 1] + cs * 10;
      const uint2 u0 = *(const uint2*)(vb + 0);
      const uint2 u1 = *(const uint2*)(vb + 2);
      const uint2 u2 = *(const uint2*)(vb + 4);
      const uint2 u3 = *(const uint2*)(vb + 6);
      const half2v p0 = BC(u0.x), p1 = BC(u0.y), p2 = BC(u1.x), p3 = BC(u1.y);
      const half2v p4 = BC(u2.x), p5 = BC(u2.y), p6 = BC(u3.x), p7 = BC(u3.y);
      DOTS8(a0, wx[0]); DOTS8(a1, wx[1]); DOTS8(a2, wx[2]); DOTS8(a3, wx[3]);
    }

    // ---- h: finish poll (2 tags/lane), stage, dots ----
    if (t > 0) {
      if (tid < 256) {
        HP_WAIT();       // raw = {pay0, tag0, pay1, tag1}
        bool ok = (raw.y == (unsigned)t) && (raw.w == (unsigned)t);
        while (!__all(ok)) {
          if (!ok) {
            __builtin_amdgcn_s_sleep(1);   // (2) backoff: de-congest the MALL
            HP_ISSUE(raw, hw4);
            HP_WAIT();
            ok = (raw.y == (unsigned)t) && (raw.w == (unsigned)t);
          }
        }
        const float h0 = __builtin_bit_cast(float, raw.x);
        const float h1 = __builtin_bit_cast(float, raw.z);
        half2v pk; pk.x = (_Float16)h0; pk.y = (_Float16)h1;
        vh16[(tid >> 3) * 10 + (tid & 7)] = __builtin_bit_cast(unsigned, pk);
      }
      __syncthreads();   // BAR1: vh staged
      {
        const unsigned* vb = vh16 + cs * 10;
        const uint2 u0 = *(const uint2*)(vb + 0);
        const uint2 u1 = *(const uint2*)(vb + 2);
        const uint2 u2 = *(const uint2*)(vb + 4);
        const uint2 u3 = *(const uint2*)(vb + 6);
        const half2v p0 = BC(u0.x), p1 = BC(u0.y), p2 = BC(u1.x), p3 = BC(u1.y);
        const half2v p4 = BC(u2.x), p5 = BC(u2.y), p6 = BC(u3.x), p7 = BC(u3.y);
        DOTS8(a0, wh[0]); DOTS8(a1, wh[1]); DOTS8(a2, wh[2]); DOTS8(a3, wh[3]);
      }
    }

    // ---- reduce across 32 k-lanes (stays within 32-lane halves) ----
    #pragma unroll
    for (int d = 1; d < 32; d <<= 1) {
      a0 += __shfl_xor(a0, d); a1 += __shfl_xor(a1, d);
      a2 += __shfl_xor(a2, d); a3 += __shfl_xor(a3, d);
    }

    // ---- gates + post (lanes cs==0: one per h-index; pre-BAR2) ----
    if (cs == 0) {
      const float gi = sigm(a0 + bs[0]);
      const float gf = sigm(a1 + bs[1]);
      const float gg = tanhx(a2 + bs[2]);
      const float go = sigm(a3 + bs[3]);
      c_state = gf * c_state + gi * gg;
      const float h = go * tanhx(c_state);
      astoreU(ringOwn + (size_t)(t & (RING - 1)) * HDIM + hq,
              ((u64)(unsigned)(t + 1) << 32) | (u64)__builtin_bit_cast(unsigned, h));
      if (layer == NL - 1) a.sout[(size_t)t * HDIM + hq] = h;
    }
    if (tid == 0 && (t & 7) == 7)
      __hip_atomic_store(myprog, (unsigned)(t + 1), __ATOMIC_RELAXED,
                         __HIP_MEMORY_SCOPE_AGENT);

    // ---- (3) finish x(t+1): tag-check + LDS stage (waves 8-15) ----
    if (xio) {
      const int w = tid - 512;
      float xv;
      if (layer == 0) {
        xv = xv0;
      } else {
        bool ok = ((unsigned)(xu >> 32) == (unsigned)(t + 2));
        while (!__all(ok)) {
          if (!ok) {
            xu = aloadU(xw);
            ok = ((unsigned)(xu >> 32) == (unsigned)(t + 2));
            if (!ok) __builtin_amdgcn_s_sleep(1);
          }
        }
        xv = __builtin_bit_cast(float, (unsigned)(xu & 0xffffffffu));
      }
      const float nb = __shfl_down(xv, 1);
      if (!(w & 1)) {
        half2v pk; pk.x = (_Float16)xv; pk.y = (_Float16)nb;
        vx16[(t + 1) & 1][(w >> 4) * 10 + ((w & 15) >> 1)] =
            __builtin_bit_cast(unsigned, pk);
      }
    }
    __syncthreads();     // BAR2
  }
}

// ---------------- MLP head: (T,512) -> 64 -> 32 -> 16 ----------------
__global__ void __launch_bounds__(64) mlp_head_kernel(
    const float* __restrict__ S,
    const float* __restrict__ w1, const float* __restrict__ b1,
    const float* __restrict__ w2, const float* __restrict__ b2,
    const float* __restrict__ w3, const float* __restrict__ b3,
    float* __restrict__ out)
{
  const int r   = blockIdx.x;
  const int tid = threadIdx.x;
  __shared__ __align__(16) float hbuf[HDIM];
  __shared__ float a1[64];
  __shared__ float a2[32];

  #pragma unroll
  for (int u = 0; u < HDIM / 64; ++u)
    hbuf[u * 64 + tid] = S[(size_t)r * HDIM + u * 64 + tid];
  __syncthreads();

  float acc = b1[tid];
  {
    const float4* w4 = (const float4*)(w1 + (size_t)tid * HDIM);
    const float4* h4 = (const float4*)hbuf;
    #pragma unroll 8
    for (int k = 0; k < HDIM / 4; ++k) {
      const float4 wv = w4[k], hv = h4[k];
      acc = fmaf(wv.x, hv.x, acc); acc = fmaf(wv.y, hv.y, acc);
      acc = fmaf(wv.z, hv.z, acc); acc = fmaf(wv.w, hv.w, acc);
    }
  }
  a1[tid] = acc * sigm(acc);
  __syncthreads();

  if (tid < 32) {
    float acc2 = b2[tid];
    #pragma unroll
    for (int k = 0; k < 64; ++k) acc2 = fmaf(a1[k], w2[tid * 64 + k], acc2);
    a2[tid] = acc2 * sigm(acc2);
  }
  __syncthreads();

  if (tid < 16) {
    float acc3 = b3[tid];
    #pragma unroll
    for (int k = 0; k < 32; ++k) acc3 = fmaf(a2[k], w3[tid * 32 + k], acc3);
    out[(size_t)r * 16 + tid] = acc3;
  }
}

// ---------------------------------------------------------------------------
extern "C" void kernel_launch(void* const* d_in, const int* in_sizes, int n_in,
                              void* d_out, int out_size, void* d_ws, size_t ws_size,
                              hipStream_t stream)
{
  (void)in_sizes; (void)n_in; (void)out_size; (void)ws_size;

  const float* x     = (const float*)d_in[0];
  const float* eWih0 = (const float*)d_in[1];
  const float* eWhh0 = (const float*)d_in[2];
  const float* ebih0 = (const float*)d_in[3];
  const float* ebhh0 = (const float*)d_in[4];
  const float* eWih  = (const float*)d_in[5];
  const float* eWhh  = (const float*)d_in[6];
  const float* ebih  = (const float*)d_in[7];
  const float* ebhh  = (const float*)d_in[8];
  const float* dWih  = (const float*)d_in[9];
  const float* dWhh  = (const float*)d_in[10];
  const float* dbih  = (const float*)d_in[11];
  const float* dbhh  = (const float*)d_in[12];
  const float* fc1w  = (const float*)d_in[13];
  const float* fc1b  = (const float*)d_in[14];
  const float* fc2w  = (const float*)d_in[15];
  const float* fc2b  = (const float*)d_in[16];
  const float* fc3w  = (const float*)d_in[17];
  const float* fc3b  = (const float*)d_in[18];
  float* out = (float*)d_out;

  // ws layout: ring 4 MB | prog (4 KB) | sout 8 MB
  const size_t RINGBYTES = (size_t)NL * RING * HDIM * sizeof(u64);  // 4 MB
  Args p{};
  p.x    = x;
  p.ring = (u64*)d_ws;
  p.prog = (unsigned*)((char*)d_ws + RINGBYTES);
  p.sout = (float*)((char*)d_ws + RINGBYTES + 4096);

  p.Wih[0] = eWih0; p.Whh[0] = eWhh0; p.bih[0] = ebih0; p.bhh[0] = ebhh0;
  for (int l = 1; l < 8; ++l) {
    p.Wih[l] = eWih + (size_t)(l - 1) * 4 * HDIM * HDIM;
    p.Whh[l] = eWhh + (size_t)(l - 1) * 4 * HDIM * HDIM;
    p.bih[l] = ebih + (size_t)(l - 1) * 4 * HDIM;
    p.bhh[l] = ebhh + (size_t)(l - 1) * 4 * HDIM;
  }
  for (int l = 8; l < 16; ++l) {
    p.Wih[l] = dWih + (size_t)(l - 8) * 4 * HDIM * HDIM;
    p.Whh[l] = dWhh + (size_t)(l - 8) * 4 * HDIM * HDIM;
    p.bih[l] = dbih + (size_t)(l - 8) * 4 * HDIM;
    p.bhh[l] = dbhh + (size_t)(l - 8) * 4 * HDIM;
  }

  // clear rings (tags) + progress flags each launch -> replay-safe
  (void)hipMemsetAsync(d_ws, 0, RINGBYTES + 4096, stream);

  void* args[] = { &p };
  hipError_t e = hipLaunchCooperativeKernel((const void*)lstm16_kernel,
                                            dim3(NL * BPL), dim3(NTH), args, 0,
                                            stream);
  if (e != hipSuccess)   // 256 blocks @ 1/CU on 256 CUs: co-resident anyway
    lstm16_kernel<<<dim3(NL * BPL), dim3(NTH), 0, stream>>>(p);

  mlp_head_kernel<<<dim3(T_SEQ), dim3(64), 0, stream>>>(
      p.sout, fc1w, fc1b, fc2w, fc2b, fc3w, fc3b, out);
}